// Round 1
// baseline (226122.705 us; speedup 1.0000x reference)
//
#include <hip/hip_runtime.h>
#include <hip/hip_bf16.h>
#include <cstdint>

#define B_ 128
#define T_ 256
#define C_ 512
#define H_ 2048
#define NWG 128
#define NTHR 256
// DT = (1/(T-1))/N_SUB = 1/765
#define DT_F 0.0013071895424836601f

typedef __bf16 bf16x8 __attribute__((ext_vector_type(8)));
typedef short s16x8 __attribute__((ext_vector_type(8)));
typedef float f32x4 __attribute__((ext_vector_type(4)));

// ---------------- workspace layout (bytes) ----------------
enum : size_t {
  OFF_FLAGS = 0,
  OFF_W1P = 4096,
  OFF_W2P = OFF_W1P + (size_t)C_ * H_ * 2,
  OFF_W3P = OFF_W2P + (size_t)H_ * H_ * 2,
  OFF_U   = OFF_W3P + (size_t)H_ * C_ * 2,
  OFF_H1  = OFF_U   + (size_t)B_ * C_ * 2,
  OFF_H2  = OFF_H1  + (size_t)B_ * H_ * 2,
  OFF_Y   = OFF_H2  + (size_t)B_ * H_ * 2,
  OFF_K1  = OFF_Y   + (size_t)B_ * C_ * 4,
  OFF_K2  = OFF_K1  + (size_t)B_ * C_ * 4,
  OFF_K3  = OFF_K2  + (size_t)B_ * C_ * 4,
  WS_END  = OFF_K3  + (size_t)B_ * C_ * 4   // ~14.2 MB
};

__device__ __forceinline__ bf16x8 ld_frag(const unsigned short* p) {
  s16x8 v = *reinterpret_cast<const s16x8*>(p);   // 16B aligned by construction
  return __builtin_bit_cast(bf16x8, v);
}
__device__ __forceinline__ f32x4 mfma16(bf16x8 a, bf16x8 b, f32x4 c) {
  return __builtin_amdgcn_mfma_f32_16x16x32_bf16(a, b, c, 0, 0, 0);
}
__device__ __forceinline__ unsigned short tobf(float f) {
  return __builtin_bit_cast(unsigned short, (__bf16)f);   // RNE fptrunc
}
__device__ __forceinline__ float fast_tanh(float v) {
  float e = __expf(2.0f * v);           // saturates correctly at +-inf
  return 1.0f - 2.0f / (e + 1.0f);
}

// ---------------- prologue kernels ----------------
__global__ void init_flags_k(unsigned* f) {
  if (threadIdx.x < NWG) f[threadIdx.x] = 0u;
}

// Pack W[K][N] fp32 -> bf16 in MFMA B-fragment order:
// packed[((nt*(K/32)+kb)*64 + lane)*8 + j] = W[kb*32 + (lane>>4)*8 + j][nt*16 + (lane&15)]
__global__ void swizzle_w_k(const float* __restrict__ W, unsigned short* __restrict__ Wp,
                            int N, int kblog) {
  int idx = blockIdx.x * 256 + threadIdx.x;
  int j = idx & 7;
  int l = (idx >> 3) & 63;
  int rem = idx >> 9;
  int kb = rem & ((1 << kblog) - 1);
  int nt = rem >> kblog;
  int k = kb * 32 + ((l >> 4) << 3) + j;
  int n = (nt << 4) + (l & 15);
  Wp[idx] = tobf(W[(size_t)k * N + n]);
}

// ---------------- grid barrier (persistent kernel, 128 co-resident WGs) ----------------
__device__ __forceinline__ void gridbar(unsigned* flags, unsigned gen) {
  __syncthreads();                                    // all WG writes drained (vmcnt0 per wave)
  __builtin_amdgcn_fence(__ATOMIC_RELEASE, "agent");  // write back L2 to coherence point
  if (threadIdx.x == 0)
    __hip_atomic_store(&flags[blockIdx.x], gen, __ATOMIC_RELAXED, __HIP_MEMORY_SCOPE_AGENT);
  if (threadIdx.x < NWG) {
    while (__hip_atomic_load(&flags[threadIdx.x], __ATOMIC_RELAXED, __HIP_MEMORY_SCOPE_AGENT) < gen)
      __builtin_amdgcn_s_sleep(2);
  }
  __syncthreads();
  __builtin_amdgcn_fence(__ATOMIC_ACQUIRE, "agent");  // invalidate L1/L2 before consuming
}

// ---------------- layer 1 / 2: [128 x K] @ [K x 2048], tanh epilogue ----------------
// 128 WGs, tile 32x64: gm = wg>>5 (4), gn = wg&31 (32). 4 waves: each 16 rows x 32 cols.
template<int K>
__device__ __forceinline__ void layer12(const unsigned short* __restrict__ A,
    const unsigned short* __restrict__ Bp, const float* __restrict__ bias,
    unsigned short* __restrict__ Hout, int wg, int wave, int lane) {
  const int lhi = lane >> 4, llo = lane & 15;
  const int gm = wg >> 5, gn = wg & 31;
  const int m16 = gm * 2 + (wave & 1);
  const int n16 = gn * 4 + ((wave >> 1) << 1);
  f32x4 acc0 = {0.f, 0.f, 0.f, 0.f}, acc1 = {0.f, 0.f, 0.f, 0.f};
  const unsigned short* ap  = A  + (size_t)(m16 * 16 + llo) * K + (lhi << 3);
  const unsigned short* bp0 = Bp + (size_t)(n16    ) * (K / 32) * 512 + lane * 8;
  const unsigned short* bp1 = Bp + (size_t)(n16 + 1) * (K / 32) * 512 + lane * 8;
  #pragma unroll 4
  for (int kb = 0; kb < K / 32; ++kb) {
    bf16x8 a   = ld_frag(ap  + kb * 32);
    bf16x8 b0v = ld_frag(bp0 + kb * 512);
    bf16x8 b1v = ld_frag(bp1 + kb * 512);
    acc0 = mfma16(a, b0v, acc0);
    acc1 = mfma16(a, b1v, acc1);
  }
  const int col0 = n16 * 16 + llo, col1 = col0 + 16;
  const float bb0 = bias[col0], bb1 = bias[col1];
  #pragma unroll
  for (int r = 0; r < 4; ++r) {
    int row = m16 * 16 + (lhi << 2) + r;   // C/D: row=(lane>>4)*4+r, col=lane&15
    Hout[(size_t)row * H_ + col0] = tobf(fast_tanh(acc0[r] + bb0));
    Hout[(size_t)row * H_ + col1] = tobf(fast_tanh(acc1[r] + bb1));
  }
}

// ---------------- layer 3: [128 x 2048] @ [2048 x 512], RK4 epilogue ----------------
// 128 WGs, tile 16x32: gm3 = wg>>4 (8), gn3 = wg&15 (16).
// waves: nsel = wave&1 picks 16-col half, khalf = wave>>1 splits K; LDS reduce.
__device__ __forceinline__ void layer3(const unsigned short* __restrict__ A,
    const unsigned short* __restrict__ Bp, const float* __restrict__ b3,
    float* __restrict__ y, float* __restrict__ k1, float* __restrict__ k2,
    float* __restrict__ k3, unsigned short* __restrict__ ubuf,
    float* __restrict__ out, int st, int sub, int t,
    int wg, int wave, int lane, float* red) {
  const int lhi = lane >> 4, llo = lane & 15;
  const int gm3 = wg >> 4, gn3 = wg & 15;
  const int khalf = wave >> 1, nsel = wave & 1;
  const int n16 = gn3 * 2 + nsel;
  f32x4 acc = {0.f, 0.f, 0.f, 0.f};
  const unsigned short* ap = A  + (size_t)(gm3 * 16 + llo) * H_ + khalf * 1024 + (lhi << 3);
  const unsigned short* bp = Bp + ((size_t)n16 * 64 + khalf * 32) * 512 + lane * 8;
  #pragma unroll 4
  for (int kb = 0; kb < 32; ++kb) {
    acc = mfma16(ld_frag(ap + kb * 32), ld_frag(bp + kb * 512), acc);
  }
  if (khalf == 1) {
    #pragma unroll
    for (int r = 0; r < 4; ++r) red[nsel * 256 + (lhi * 4 + r) * 16 + llo] = acc[r];
  }
  __syncthreads();
  if (khalf == 0) {
    const float dt = DT_F;
    const float bb = b3[n16 * 16 + llo];
    #pragma unroll
    for (int r = 0; r < 4; ++r) {
      int row = gm3 * 16 + (lhi << 2) + r;
      int col = n16 * 16 + llo;
      int idx = row * C_ + col;
      float z = acc[r] + red[nsel * 256 + (lhi * 4 + r) * 16 + llo] + bb;
      if (st == 0)      { k1[idx] = z; ubuf[idx] = tobf(y[idx] + 0.5f * dt * z); }
      else if (st == 1) { k2[idx] = z; ubuf[idx] = tobf(y[idx] + 0.5f * dt * z); }
      else if (st == 2) { k3[idx] = z; ubuf[idx] = tobf(y[idx] + dt * z); }
      else {
        float yn = y[idx] + (dt * (1.0f / 6.0f)) * (k1[idx] + 2.f * k2[idx] + 2.f * k3[idx] + z);
        y[idx] = yn;
        ubuf[idx] = tobf(yn);
        if (sub == 2) out[(size_t)row * (T_ * C_) + (t + 1) * C_ + col] = yn;
      }
    }
  }
  // red reuse protected by the grid barrier's __syncthreads after this call
}

// ---------------- persistent ODE kernel ----------------
__global__ __launch_bounds__(NTHR) void ode_persist_k(
    const float* __restrict__ x, const float* __restrict__ b1,
    const float* __restrict__ b2, const float* __restrict__ b3,
    float* __restrict__ out, unsigned char* __restrict__ ws) {
  unsigned* flags = (unsigned*)(ws + OFF_FLAGS);
  const unsigned short* W1p = (const unsigned short*)(ws + OFF_W1P);
  const unsigned short* W2p = (const unsigned short*)(ws + OFF_W2P);
  const unsigned short* W3p = (const unsigned short*)(ws + OFF_W3P);
  unsigned short* ubuf = (unsigned short*)(ws + OFF_U);
  unsigned short* h1   = (unsigned short*)(ws + OFF_H1);
  unsigned short* h2   = (unsigned short*)(ws + OFF_H2);
  float* y  = (float*)(ws + OFF_Y);
  float* k1 = (float*)(ws + OFF_K1);
  float* k2 = (float*)(ws + OFF_K2);
  float* k3 = (float*)(ws + OFF_K3);
  __shared__ float red[512];

  const int wg = blockIdx.x, tid = threadIdx.x;
  const int wave = tid >> 6, lane = tid & 63;
  unsigned gen = 0;

  // init: y = x[:,0,:]; ubuf = bf16(y); out[:,0,:] = x[:,0,:]
  for (int i = wg * NTHR + tid; i < B_ * C_; i += NWG * NTHR) {
    int b = i >> 9, c = i & (C_ - 1);
    float v = x[(size_t)b * (T_ * C_) + c];
    y[i] = v;
    ubuf[i] = tobf(v);
    out[(size_t)b * (T_ * C_) + c] = v;
  }
  gridbar(flags, ++gen);

  #pragma unroll 1
  for (int t = 0; t < T_ - 1; ++t) {
    #pragma unroll 1
    for (int sub = 0; sub < 3; ++sub) {
      #pragma unroll 1
      for (int st = 0; st < 4; ++st) {
        layer12<C_>(ubuf, W1p, b1, h1, wg, wave, lane);
        gridbar(flags, ++gen);
        layer12<H_>(h1, W2p, b2, h2, wg, wave, lane);
        gridbar(flags, ++gen);
        layer3(h2, W3p, b3, y, k1, k2, k3, ubuf, out, st, sub, t, wg, wave, lane, red);
        gridbar(flags, ++gen);
      }
    }
  }
}

// ---------------- host ----------------
extern "C" void kernel_launch(void* const* d_in, const int* in_sizes, int n_in,
                              void* d_out, int out_size, void* d_ws, size_t ws_size,
                              hipStream_t stream) {
  (void)in_sizes; (void)n_in; (void)out_size; (void)ws_size;
  const float* x  = (const float*)d_in[0];
  const float* W1 = (const float*)d_in[1];
  const float* b1 = (const float*)d_in[2];
  const float* W2 = (const float*)d_in[3];
  const float* b2 = (const float*)d_in[4];
  const float* W3 = (const float*)d_in[5];
  const float* b3 = (const float*)d_in[6];
  float* out = (float*)d_out;
  unsigned char* ws = (unsigned char*)d_ws;

  init_flags_k<<<1, 128, 0, stream>>>((unsigned*)(ws + OFF_FLAGS));
  // W1: K=512 (kblog=4), N=2048 ; W2: K=2048 (kblog=6), N=2048 ; W3: K=2048 (kblog=6), N=512
  swizzle_w_k<<<(C_ * H_) / 256, 256, 0, stream>>>(W1, (unsigned short*)(ws + OFF_W1P), H_, 4);
  swizzle_w_k<<<(H_ * H_) / 256, 256, 0, stream>>>(W2, (unsigned short*)(ws + OFF_W2P), H_, 6);
  swizzle_w_k<<<(H_ * C_) / 256, 256, 0, stream>>>(W3, (unsigned short*)(ws + OFF_W3P), C_, 6);

  ode_persist_k<<<NWG, NTHR, 0, stream>>>(x, b1, b2, b3, out, ws);
}

// Round 2
// 150307.202 us; speedup vs baseline: 1.5044x; 1.5044x over previous
//
#include <hip/hip_runtime.h>
#include <hip/hip_bf16.h>
#include <cstdint>

#define B_ 128
#define T_ 256
#define C_ 512
#define H_ 2048
#define NWG 128
#define NTHR 256
// DT = (1/(T-1))/N_SUB = 1/765
#define DT_F 0.0013071895424836601f

typedef __bf16 bf16x8 __attribute__((ext_vector_type(8)));
typedef short s16x8 __attribute__((ext_vector_type(8)));
typedef float f32x4 __attribute__((ext_vector_type(4)));

// ---------------- workspace layout (bytes) ----------------
enum : size_t {
  OFF_FLAGS = 0,
  OFF_W1P = 4096,
  OFF_W2P = OFF_W1P + (size_t)C_ * H_ * 2,
  OFF_W3P = OFF_W2P + (size_t)H_ * H_ * 2,
  OFF_U   = OFF_W3P + (size_t)H_ * C_ * 2,
  OFF_H1  = OFF_U   + (size_t)B_ * C_ * 2,
  OFF_H2  = OFF_H1  + (size_t)B_ * H_ * 2,
  OFF_Y   = OFF_H2  + (size_t)B_ * H_ * 2,
  OFF_K1  = OFF_Y   + (size_t)B_ * C_ * 4,
  OFF_K2  = OFF_K1  + (size_t)B_ * C_ * 4,
  OFF_K3  = OFF_K2  + (size_t)B_ * C_ * 4,
  WS_END  = OFF_K3  + (size_t)B_ * C_ * 4   // ~14.2 MB
};

// plain cached 16B load (weights: read-only, L1/L2 resident)
__device__ __forceinline__ bf16x8 ld_frag(const unsigned short* p) {
  s16x8 v = *reinterpret_cast<const s16x8*>(p);
  return __builtin_bit_cast(bf16x8, v);
}
// coherent 16B load (activations: bypass stale L1/L2, read MALL coherence point)
__device__ __forceinline__ bf16x8 ld_frag_coh(const unsigned short* p) {
  struct U { unsigned long long a, b; } u;
  u.a = __hip_atomic_load((const unsigned long long*)p,     __ATOMIC_RELAXED, __HIP_MEMORY_SCOPE_AGENT);
  u.b = __hip_atomic_load((const unsigned long long*)p + 1, __ATOMIC_RELAXED, __HIP_MEMORY_SCOPE_AGENT);
  return __builtin_bit_cast(bf16x8, u);
}
// coherent 2B store (activations: write-through to coherence point)
__device__ __forceinline__ void st_coh16(unsigned short* p, unsigned short v) {
  __hip_atomic_store(p, v, __ATOMIC_RELAXED, __HIP_MEMORY_SCOPE_AGENT);
}
__device__ __forceinline__ f32x4 mfma16(bf16x8 a, bf16x8 b, f32x4 c) {
  return __builtin_amdgcn_mfma_f32_16x16x32_bf16(a, b, c, 0, 0, 0);
}
__device__ __forceinline__ unsigned short tobf(float f) {
  return __builtin_bit_cast(unsigned short, (__bf16)f);   // RNE fptrunc
}
__device__ __forceinline__ float fast_tanh(float v) {
  float e = __expf(2.0f * v);
  return 1.0f - 2.0f / (e + 1.0f);
}

// ---------------- prologue kernels ----------------
__global__ void init_flags_k(unsigned* f) {
  if (threadIdx.x < NWG) f[threadIdx.x] = 0u;
}

// Pack W[K][N] fp32 -> bf16 in MFMA B-fragment order:
// packed[((nt*(K/32)+kb)*64 + lane)*8 + j] = W[kb*32 + (lane>>4)*8 + j][nt*16 + (lane&15)]
__global__ void swizzle_w_k(const float* __restrict__ W, unsigned short* __restrict__ Wp,
                            int N, int kblog) {
  int idx = blockIdx.x * 256 + threadIdx.x;
  int j = idx & 7;
  int l = (idx >> 3) & 63;
  int rem = idx >> 9;
  int kb = rem & ((1 << kblog) - 1);
  int nt = rem >> kblog;
  int k = kb * 32 + ((l >> 4) << 3) + j;
  int n = (nt << 4) + (l & 15);
  Wp[idx] = tobf(W[(size_t)k * N + n]);
}

// ---------------- grid barrier: NO cache-nuking fences ----------------
// All cross-WG data moves via agent-scope (sc0 sc1) atomics that hit the MALL
// coherence point directly, so release==drain own stores (vmcnt 0) and
// acquire==nothing (coherent loads bypass stale caches). Weights stay warm in L1/L2.
__device__ __forceinline__ void gridbar(unsigned* flags, unsigned gen) {
  asm volatile("s_waitcnt vmcnt(0)" ::: "memory");   // drain this wave's stores
  __syncthreads();                                   // all waves drained
  if (threadIdx.x == 0)
    __hip_atomic_store(&flags[blockIdx.x], gen, __ATOMIC_RELAXED, __HIP_MEMORY_SCOPE_AGENT);
  if (threadIdx.x < NWG) {
    while (__hip_atomic_load(&flags[threadIdx.x], __ATOMIC_RELAXED, __HIP_MEMORY_SCOPE_AGENT) < gen)
      __builtin_amdgcn_s_sleep(2);
  }
  __syncthreads();
}

// ---------------- layer 1 / 2: [128 x K] @ [K x 2048], tanh epilogue ----------------
// tile 32x64 per WG. 4 waves: each 16 rows x 32 cols (2 accs).
template<int K>
__device__ __forceinline__ void layer12(const unsigned short* __restrict__ A,
    const unsigned short* __restrict__ Bp, const float* __restrict__ bias,
    unsigned short* __restrict__ Hout, int gm, int gn, int wave, int lane) {
  const int lhi = lane >> 4, llo = lane & 15;
  const int m16 = gm * 2 + (wave & 1);
  const int n16 = gn * 4 + ((wave >> 1) << 1);
  f32x4 acc0 = {0.f, 0.f, 0.f, 0.f}, acc1 = {0.f, 0.f, 0.f, 0.f};
  const unsigned short* ap  = A  + (size_t)(m16 * 16 + llo) * K + (lhi << 3);
  const unsigned short* bp0 = Bp + (size_t)(n16    ) * (K / 32) * 512 + lane * 8;
  const unsigned short* bp1 = Bp + (size_t)(n16 + 1) * (K / 32) * 512 + lane * 8;
  #pragma unroll 8
  for (int kb = 0; kb < K / 32; ++kb) {
    bf16x8 a   = ld_frag_coh(ap + kb * 32);        // activation: coherent
    bf16x8 b0v = ld_frag(bp0 + kb * 512);          // weight: cached
    bf16x8 b1v = ld_frag(bp1 + kb * 512);
    acc0 = mfma16(a, b0v, acc0);
    acc1 = mfma16(a, b1v, acc1);
  }
  const int col0 = n16 * 16 + llo, col1 = col0 + 16;
  const float bb0 = bias[col0], bb1 = bias[col1];
  #pragma unroll
  for (int r = 0; r < 4; ++r) {
    int row = m16 * 16 + (lhi << 2) + r;   // C/D: row=(lane>>4)*4+r, col=lane&15
    st_coh16(&Hout[(size_t)row * H_ + col0], tobf(fast_tanh(acc0[r] + bb0)));
    st_coh16(&Hout[(size_t)row * H_ + col1], tobf(fast_tanh(acc1[r] + bb1)));
  }
}

// ---------------- layer 3: [128 x 2048] @ [2048 x 512], RK4 epilogue ----------------
// tile 16x32 per WG: gm3 = wg>>4 (8), gn3 = wg&15 (16). Wave K-split + LDS reduce.
__device__ __forceinline__ void layer3(const unsigned short* __restrict__ A,
    const unsigned short* __restrict__ Bp, const float* __restrict__ b3,
    float* __restrict__ y, float* __restrict__ k1, float* __restrict__ k2,
    float* __restrict__ k3, unsigned short* __restrict__ ubuf,
    float* __restrict__ out, int st, int sub, int t,
    int gm3, int gn3, int wave, int lane, float* red) {
  const int lhi = lane >> 4, llo = lane & 15;
  const int khalf = wave >> 1, nsel = wave & 1;
  const int n16 = gn3 * 2 + nsel;
  f32x4 acc = {0.f, 0.f, 0.f, 0.f};
  const unsigned short* ap = A  + (size_t)(gm3 * 16 + llo) * H_ + khalf * 1024 + (lhi << 3);
  const unsigned short* bp = Bp + ((size_t)n16 * 64 + khalf * 32) * 512 + lane * 8;
  #pragma unroll 8
  for (int kb = 0; kb < 32; ++kb) {
    acc = mfma16(ld_frag_coh(ap + kb * 32), ld_frag(bp + kb * 512), acc);
  }
  if (khalf == 1) {
    #pragma unroll
    for (int r = 0; r < 4; ++r) red[nsel * 256 + (lhi * 4 + r) * 16 + llo] = acc[r];
  }
  __syncthreads();
  if (khalf == 0) {
    const float dt = DT_F;
    const float bb = b3[n16 * 16 + llo];
    #pragma unroll
    for (int r = 0; r < 4; ++r) {
      int row = gm3 * 16 + (lhi << 2) + r;
      int col = n16 * 16 + llo;
      int idx = row * C_ + col;
      float z = acc[r] + red[nsel * 256 + (lhi * 4 + r) * 16 + llo] + bb;
      if (st == 0)      { k1[idx] = z; st_coh16(&ubuf[idx], tobf(y[idx] + 0.5f * dt * z)); }
      else if (st == 1) { k2[idx] = z; st_coh16(&ubuf[idx], tobf(y[idx] + 0.5f * dt * z)); }
      else if (st == 2) { k3[idx] = z; st_coh16(&ubuf[idx], tobf(y[idx] + dt * z)); }
      else {
        float yn = y[idx] + (dt * (1.0f / 6.0f)) * (k1[idx] + 2.f * k2[idx] + 2.f * k3[idx] + z);
        y[idx] = yn;                                   // WG-private: plain cached
        st_coh16(&ubuf[idx], tobf(yn));
        if (sub == 2) out[(size_t)row * (T_ * C_) + (t + 1) * C_ + col] = yn;
      }
    }
  }
  // red reuse protected by the grid barrier's __syncthreads after this call
}

// ---------------- persistent ODE kernel ----------------
__global__ __launch_bounds__(NTHR, 1) void ode_persist_k(
    const float* __restrict__ x, const float* __restrict__ b1,
    const float* __restrict__ b2, const float* __restrict__ b3,
    float* __restrict__ out, unsigned char* __restrict__ ws) {
  unsigned* flags = (unsigned*)(ws + OFF_FLAGS);
  const unsigned short* W1p = (const unsigned short*)(ws + OFF_W1P);
  const unsigned short* W2p = (const unsigned short*)(ws + OFF_W2P);
  const unsigned short* W3p = (const unsigned short*)(ws + OFF_W3P);
  unsigned short* ubuf = (unsigned short*)(ws + OFF_U);
  unsigned short* h1   = (unsigned short*)(ws + OFF_H1);
  unsigned short* h2   = (unsigned short*)(ws + OFF_H2);
  float* y  = (float*)(ws + OFF_Y);
  float* k1 = (float*)(ws + OFF_K1);
  float* k2 = (float*)(ws + OFF_K2);
  float* k3 = (float*)(ws + OFF_K3);
  __shared__ float red[512];

  const int wg = blockIdx.x, tid = threadIdx.x;
  const int wave = tid >> 6, lane = tid & 63;
  // XCD-aware swizzle for layers 1/2: the 4 WGs sharing a gn (same weight
  // columns) land on the same XCD (wg % 8 == XCD id, spacing 8 keeps XCD fixed)
  // -> per-XCD W2 working set ~1 MB, L2-resident.
  const int gm = (wg >> 3) & 3;
  const int gn = (wg & 7) | ((wg >> 5) << 3);
  const int gm3 = wg >> 4, gn3 = wg & 15;
  unsigned gen = 0;

  // init: y = x[:,0,:]; ubuf = bf16(y); out[:,0,:] = x[:,0,:]
  for (int i = wg * NTHR + tid; i < B_ * C_; i += NWG * NTHR) {
    int b = i >> 9, c = i & (C_ - 1);
    float v = x[(size_t)b * (T_ * C_) + c];
    y[i] = v;                 // y is re-read only by this WG? (striped init: owner
                              // differs from layer3 owner) -> but y rows are only
                              // READ in layer3 by the WG that also WROTE them in
                              // layer3... first read is by layer3 owner: make it coherent.
    st_coh16(&ubuf[i], tobf(v));
    out[(size_t)b * (T_ * C_) + c] = v;
  }
  // y init crosses WGs (striped init vs tiled layer3 ownership): publish via
  // coherent stores as well. Redo y with atomic store to be safe.
  for (int i = wg * NTHR + tid; i < B_ * C_; i += NWG * NTHR) {
    __hip_atomic_store(&((unsigned*)y)[i], __builtin_bit_cast(unsigned, y[i]),
                       __ATOMIC_RELAXED, __HIP_MEMORY_SCOPE_AGENT);
  }
  gridbar(flags, ++gen);
  // first touch of y by its layer3 owner must bypass stale cache: owner has no
  // cached copy yet (first access), so plain loads are safe from here on.

  #pragma unroll 1
  for (int t = 0; t < T_ - 1; ++t) {
    #pragma unroll 1
    for (int sub = 0; sub < 3; ++sub) {
      #pragma unroll 1
      for (int st = 0; st < 4; ++st) {
        layer12<C_>(ubuf, W1p, b1, h1, gm, gn, wave, lane);
        gridbar(flags, ++gen);
        layer12<H_>(h1, W2p, b2, h2, gm, gn, wave, lane);
        gridbar(flags, ++gen);
        layer3(h2, W3p, b3, y, k1, k2, k3, ubuf, out, st, sub, t,
               gm3, gn3, wave, lane, red);
        gridbar(flags, ++gen);
      }
    }
  }
}

// ---------------- host ----------------
extern "C" void kernel_launch(void* const* d_in, const int* in_sizes, int n_in,
                              void* d_out, int out_size, void* d_ws, size_t ws_size,
                              hipStream_t stream) {
  (void)in_sizes; (void)n_in; (void)out_size; (void)ws_size;
  const float* x  = (const float*)d_in[0];
  const float* W1 = (const float*)d_in[1];
  const float* b1 = (const float*)d_in[2];
  const float* W2 = (const float*)d_in[3];
  const float* b2 = (const float*)d_in[4];
  const float* W3 = (const float*)d_in[5];
  const float* b3 = (const float*)d_in[6];
  float* out = (float*)d_out;
  unsigned char* ws = (unsigned char*)d_ws;

  init_flags_k<<<1, 128, 0, stream>>>((unsigned*)(ws + OFF_FLAGS));
  // W1: K=512 (kblog=4), N=2048 ; W2: K=2048 (kblog=6), N=2048 ; W3: K=2048 (kblog=6), N=512
  swizzle_w_k<<<(C_ * H_) / 256, 256, 0, stream>>>(W1, (unsigned short*)(ws + OFF_W1P), H_, 4);
  swizzle_w_k<<<(H_ * H_) / 256, 256, 0, stream>>>(W2, (unsigned short*)(ws + OFF_W2P), H_, 6);
  swizzle_w_k<<<(H_ * C_) / 256, 256, 0, stream>>>(W3, (unsigned short*)(ws + OFF_W3P), C_, 6);

  ode_persist_k<<<NWG, NTHR, 0, stream>>>(x, b1, b2, b3, out, ws);
}

// Round 3
// 58268.463 us; speedup vs baseline: 3.8807x; 2.5796x over previous
//
#include <hip/hip_runtime.h>
#include <hip/hip_bf16.h>
#include <cstdint>

#define B_ 128
#define T_ 256
#define C_ 512
#define H_ 2048
#define NWG 256
#define NTHR 256
#define NGROUP 8
#define GSIZE 32        // WGs per row-group
#define M_ 16           // batch rows per group
// DT = (1/(T-1))/N_SUB = 1/765
#define DT_F 0.0013071895424836601f

typedef __bf16 bf16x8 __attribute__((ext_vector_type(8)));
typedef short s16x8 __attribute__((ext_vector_type(8)));
typedef float f32x4 __attribute__((ext_vector_type(4)));
typedef unsigned long long ull;

// ---------------- workspace layout (bytes) ----------------
enum : size_t {
  OFF_FLAGS = 0,                                   // 8 groups * 64 u32 = 2 KB
  OFF_W1P = 4096,
  OFF_W2P = OFF_W1P + (size_t)C_ * H_ * 2,         // 2 MB
  OFF_W3P = OFF_W2P + (size_t)H_ * H_ * 2,         // 8 MB
  OFF_U   = OFF_W3P + (size_t)H_ * C_ * 2,         // 2 MB
  OFF_H1  = OFF_U   + (size_t)NGROUP * M_ * C_ * 2, // 128 KB
  OFF_H2  = OFF_H1  + (size_t)NGROUP * M_ * H_ * 2, // 512 KB
  WS_END  = OFF_H2  + (size_t)NGROUP * M_ * H_ * 2  // ~13.3 MB total
};

__device__ __forceinline__ bf16x8 ld_frag(const unsigned short* p) {   // cached (weights)
  s16x8 v = *reinterpret_cast<const s16x8*>(p);
  return __builtin_bit_cast(bf16x8, v);
}
__device__ __forceinline__ bf16x8 lds_frag(const unsigned short* p) {  // ds_read_b128
  s16x8 v = *reinterpret_cast<const s16x8*>(p);
  return __builtin_bit_cast(bf16x8, v);
}
__device__ __forceinline__ void st_coh16(unsigned short* p, unsigned short v) {
  __hip_atomic_store(p, v, __ATOMIC_RELAXED, __HIP_MEMORY_SCOPE_AGENT);
}
__device__ __forceinline__ f32x4 mfma16(bf16x8 a, bf16x8 b, f32x4 c) {
  return __builtin_amdgcn_mfma_f32_16x16x32_bf16(a, b, c, 0, 0, 0);
}
__device__ __forceinline__ unsigned short tobf(float f) {
  return __builtin_bit_cast(unsigned short, (__bf16)f);
}
__device__ __forceinline__ float fast_tanh(float v) {
  float e = __expf(2.0f * v);
  return 1.0f - 2.0f / (e + 1.0f);
}

// ---------------- prologue kernels ----------------
__global__ void init_flags_k(unsigned* f) {
  if (threadIdx.x < NGROUP * 64) f[threadIdx.x] = 0u;
}

// Pack W[K][N] fp32 -> bf16 in MFMA B-fragment order (validated rounds 1-2):
// packed[((nt*(K/32)+kb)*64 + lane)*8 + j] = W[kb*32 + (lane>>4)*8 + j][nt*16 + (lane&15)]
__global__ void swizzle_w_k(const float* __restrict__ W, unsigned short* __restrict__ Wp,
                            int N, int kblog) {
  int idx = blockIdx.x * 256 + threadIdx.x;
  int j = idx & 7;
  int l = (idx >> 3) & 63;
  int rem = idx >> 9;
  int kb = rem & ((1 << kblog) - 1);
  int nt = rem >> kblog;
  int k = kb * 32 + ((l >> 4) << 3) + j;
  int n = (nt << 4) + (l & 15);
  Wp[idx] = tobf(W[(size_t)k * N + n]);
}

// ---------------- group-local barrier (32 WGs), MALL-coherent flags ----------------
__device__ __forceinline__ void groupbar(unsigned* gflags, int gn, unsigned gen) {
  asm volatile("s_waitcnt vmcnt(0)" ::: "memory");   // this wave's coherent stores visible
  __syncthreads();                                   // all waves drained
  if (threadIdx.x == 0)
    __hip_atomic_store(&gflags[gn], gen, __ATOMIC_RELAXED, __HIP_MEMORY_SCOPE_AGENT);
  if (threadIdx.x < GSIZE) {
    while (__hip_atomic_load(&gflags[threadIdx.x], __ATOMIC_RELAXED, __HIP_MEMORY_SCOPE_AGENT) < gen)
      __builtin_amdgcn_s_sleep(1);
  }
  __syncthreads();
}

// ---------------- batched coherent stage: global [M_ x GU ull] -> LDS [M_ x (TU+2) ull] ----
template<int TU, int GU>   // TU = tile ull/row, GU = global ull/row
__device__ __forceinline__ void stage_tile(const ull* __restrict__ g,
                                           ull* __restrict__ lds, int tid) {
  constexpr int CNT = (M_ * TU) / NTHR;
  ull v[CNT];
  #pragma unroll
  for (int j = 0; j < CNT; ++j) {          // all loads issue back-to-back (one wait)
    int i = j * NTHR + tid;
    int row = i / TU, col = i % TU;        // TU power-of-2 -> shifts
    v[j] = __hip_atomic_load(g + (size_t)row * GU + col,
                             __ATOMIC_RELAXED, __HIP_MEMORY_SCOPE_AGENT);
  }
  #pragma unroll
  for (int j = 0; j < CNT; ++j) {
    int i = j * NTHR + tid;
    int row = i / TU, col = i % TU;
    lds[row * (TU + 2) + col] = v[j];      // +2 ull pad -> conflict-friendly stride
  }
}

// ---------------- persistent ODE kernel ----------------
// 8 groups x 32 WGs. Group g owns batch rows [16g,16g+16). No cross-group sync.
__global__ __launch_bounds__(NTHR, 1) void ode_persist_k(
    const float* __restrict__ x, const float* __restrict__ b1,
    const float* __restrict__ b2, const float* __restrict__ b3,
    float* __restrict__ out, unsigned char* __restrict__ ws) {
  const int wg = blockIdx.x, tid = threadIdx.x;
  const int g = wg >> 5, gn = wg & 31;     // XCD = wg%8 = gn%8: B-slices shared per XCD
  const int wave = tid >> 6, lane = tid & 63;
  const int lhi = lane >> 4, llo = lane & 15;

  unsigned* gflags = (unsigned*)(ws + OFF_FLAGS) + g * 64;
  const unsigned short* W1p = (const unsigned short*)(ws + OFF_W1P);
  const unsigned short* W2p = (const unsigned short*)(ws + OFF_W2P);
  const unsigned short* W3p = (const unsigned short*)(ws + OFF_W3P);
  const ull* ubuf_u = (const ull*)(ws + OFF_U)  + (size_t)g * (M_ * C_ / 4);
  const ull* h1_u   = (const ull*)(ws + OFF_H1) + (size_t)g * (M_ * H_ / 4);
  const ull* h2_u   = (const ull*)(ws + OFF_H2) + (size_t)g * (M_ * H_ / 4);
  unsigned short* ubuf_s = (unsigned short*)(ws + OFF_U)  + (size_t)g * M_ * C_;
  unsigned short* h1_s   = (unsigned short*)(ws + OFF_H1) + (size_t)g * M_ * H_;
  unsigned short* h2_s   = (unsigned short*)(ws + OFF_H2) + (size_t)g * M_ * H_;

  __shared__ alignas(16) ull atile[M_ * 258];   // 33 KB: 16 x (256+2) ull chunks
  __shared__ float red[4][256];
  __shared__ float ytile[256], k1t[256], k2t[256], k3t[256];

  // ---- init: y tile from x, out[:,0,:], ubuf = bf16(y) ----
  {
    int row = tid >> 4, c16 = tid & 15;
    int col = gn * 16 + c16;
    int b = g * M_ + row;
    float v = x[(size_t)b * (T_ * C_) + col];
    ytile[tid] = v;                                  // NB: tid == row*16+c16
    out[(size_t)b * (T_ * C_) + col] = v;
    st_coh16(&ubuf_s[row * C_ + col], tobf(v));
  }
  unsigned gen = 0;
  groupbar(gflags, gn, ++gen);

  #pragma unroll 1
  for (int t = 0; t < T_ - 1; ++t) {
    #pragma unroll 1
    for (int sub = 0; sub < 3; ++sub) {
      #pragma unroll 1
      for (int st = 0; st < 4; ++st) {
        // ---- layer 1: [16x512]@[512x2048], tanh ----
        stage_tile<128, 128>(ubuf_u, atile, tid);
        __syncthreads();
        {
          const int n16 = gn * 4 + wave;
          f32x4 acc = {0.f, 0.f, 0.f, 0.f};
          const unsigned short* al = (const unsigned short*)atile + llo * 520 + lhi * 8;
          const unsigned short* bp = W1p + (size_t)n16 * 16 * 512 + lane * 8;
          #pragma unroll
          for (int kb = 0; kb < 16; ++kb)
            acc = mfma16(lds_frag(al + kb * 32), ld_frag(bp + kb * 512), acc);
          const int col = n16 * 16 + llo;
          const float bb = b1[col];
          #pragma unroll
          for (int r = 0; r < 4; ++r)
            st_coh16(&h1_s[(lhi * 4 + r) * H_ + col], tobf(fast_tanh(acc[r] + bb)));
        }
        groupbar(gflags, gn, ++gen);

        // ---- layer 2: [16x2048]@[2048x2048], tanh (2 K-chunks) ----
        {
          const int n16 = gn * 4 + wave;
          f32x4 acc = {0.f, 0.f, 0.f, 0.f};
          const unsigned short* bp = W2p + (size_t)n16 * 64 * 512 + lane * 8;
          #pragma unroll 1
          for (int c = 0; c < 2; ++c) {
            if (c) __syncthreads();                  // all waves done with chunk 0
            stage_tile<256, 512>(h1_u + c * 256, atile, tid);
            __syncthreads();
            const unsigned short* al = (const unsigned short*)atile + llo * 1032 + lhi * 8;
            #pragma unroll
            for (int kb = 0; kb < 32; ++kb)
              acc = mfma16(lds_frag(al + kb * 32), ld_frag(bp + (c * 32 + kb) * 512), acc);
          }
          const int col = n16 * 16 + llo;
          const float bb = b2[col];
          #pragma unroll
          for (int r = 0; r < 4; ++r)
            st_coh16(&h2_s[(lhi * 4 + r) * H_ + col], tobf(fast_tanh(acc[r] + bb)));
        }
        groupbar(gflags, gn, ++gen);

        // ---- layer 3: [16x2048]@[2048x512], wave K-split, RK4 epilogue ----
        {
          f32x4 acc = {0.f, 0.f, 0.f, 0.f};
          const unsigned short* bp = W3p + (size_t)gn * 64 * 512 + lane * 8;
          #pragma unroll 1
          for (int c = 0; c < 2; ++c) {
            if (c) __syncthreads();
            stage_tile<256, 512>(h2_u + c * 256, atile, tid);
            __syncthreads();
            const unsigned short* al = (const unsigned short*)atile + llo * 1032 + lhi * 8;
            #pragma unroll
            for (int jj = 0; jj < 8; ++jj) {
              int kb = wave * 8 + jj;                // wave splits K within chunk
              acc = mfma16(lds_frag(al + kb * 32), ld_frag(bp + (c * 32 + kb) * 512), acc);
            }
          }
          #pragma unroll
          for (int r = 0; r < 4; ++r) red[wave][(lhi * 4 + r) * 16 + llo] = acc[r];
          __syncthreads();
          if (wave == 0) {
            const float dt = DT_F;
            const float bb = b3[gn * 16 + llo];
            #pragma unroll
            for (int r = 0; r < 4; ++r) {
              int row = lhi * 4 + r;
              int i = row * 16 + llo;
              float z = red[0][i] + red[1][i] + red[2][i] + red[3][i] + bb;
              float yv = ytile[i];
              unsigned short* up = &ubuf_s[row * C_ + gn * 16 + llo];
              if (st == 0)      { k1t[i] = z; st_coh16(up, tobf(yv + 0.5f * dt * z)); }
              else if (st == 1) { k2t[i] = z; st_coh16(up, tobf(yv + 0.5f * dt * z)); }
              else if (st == 2) { k3t[i] = z; st_coh16(up, tobf(yv + dt * z)); }
              else {
                float yn = yv + (dt * (1.0f / 6.0f)) * (k1t[i] + 2.f * k2t[i] + 2.f * k3t[i] + z);
                ytile[i] = yn;
                st_coh16(up, tobf(yn));
                if (sub == 2)
                  out[(size_t)(g * M_ + row) * (T_ * C_) + (size_t)(t + 1) * C_ + gn * 16 + llo] = yn;
              }
            }
          }
        }
        groupbar(gflags, gn, ++gen);
      }
    }
  }
}

// ---------------- host ----------------
extern "C" void kernel_launch(void* const* d_in, const int* in_sizes, int n_in,
                              void* d_out, int out_size, void* d_ws, size_t ws_size,
                              hipStream_t stream) {
  (void)in_sizes; (void)n_in; (void)out_size; (void)ws_size;
  const float* x  = (const float*)d_in[0];
  const float* W1 = (const float*)d_in[1];
  const float* b1 = (const float*)d_in[2];
  const float* W2 = (const float*)d_in[3];
  const float* b2 = (const float*)d_in[4];
  const float* W3 = (const float*)d_in[5];
  const float* b3 = (const float*)d_in[6];
  float* out = (float*)d_out;
  unsigned char* ws = (unsigned char*)d_ws;

  init_flags_k<<<1, 512, 0, stream>>>((unsigned*)(ws + OFF_FLAGS));
  // W1: K=512 (kblog=4), N=2048 ; W2: K=2048 (kblog=6), N=2048 ; W3: K=2048 (kblog=6), N=512
  swizzle_w_k<<<(C_ * H_) / 256, 256, 0, stream>>>(W1, (unsigned short*)(ws + OFF_W1P), H_, 4);
  swizzle_w_k<<<(H_ * H_) / 256, 256, 0, stream>>>(W2, (unsigned short*)(ws + OFF_W2P), H_, 6);
  swizzle_w_k<<<(H_ * C_) / 256, 256, 0, stream>>>(W3, (unsigned short*)(ws + OFF_W3P), C_, 6);

  ode_persist_k<<<NWG, NTHR, 0, stream>>>(x, b1, b2, b3, out, ws);
}

// Round 4
// 51846.796 us; speedup vs baseline: 4.3614x; 1.1239x over previous
//
#include <hip/hip_runtime.h>
#include <hip/hip_bf16.h>
#include <cstdint>

#define B_ 128
#define T_ 256
#define C_ 512
#define H_ 2048
#define NWG 256
#define NTHR 256
#define NGROUP 8
#define GSIZE 32        // WGs per row-group
#define M_ 16           // batch rows per group
#define FSTRIDE 16      // flag padding (dwords) -> 64 B per flag
#define RSU 134         // atile row stride in ull: 268 dwords == 12 mod 32 -> min-conflict, 16B-aligned
#define RSS 536         // row stride in shorts (RSU*4)
// DT = (1/(T-1))/N_SUB = 1/765
#define DT_F 0.0013071895424836601f

typedef __bf16 bf16x8 __attribute__((ext_vector_type(8)));
typedef short s16x8 __attribute__((ext_vector_type(8)));
typedef float f32x4 __attribute__((ext_vector_type(4)));
typedef unsigned long long ull;

// ---------------- workspace layout (bytes) ----------------
enum : size_t {
  OFF_FLAGS = 0,                                    // 8 groups * 32 flags * 64 B = 16 KB
  OFF_W1P = 32768,
  OFF_W2P = OFF_W1P + (size_t)C_ * H_ * 2,          // 2 MB
  OFF_W3P = OFF_W2P + (size_t)H_ * H_ * 2,          // 8 MB
  OFF_U   = OFF_W3P + (size_t)H_ * C_ * 2,          // 2 MB
  OFF_H1  = OFF_U   + (size_t)NGROUP * M_ * C_ * 2, // 128 KB
  OFF_H2  = OFF_H1  + (size_t)NGROUP * M_ * H_ * 2, // 512 KB
  WS_END  = OFF_H2  + (size_t)NGROUP * M_ * H_ * 2  // ~13.4 MB
};

__device__ __forceinline__ bf16x8 ld_frag(const unsigned short* p) {   // cached (weights)
  s16x8 v = *reinterpret_cast<const s16x8*>(p);
  return __builtin_bit_cast(bf16x8, v);
}
__device__ __forceinline__ bf16x8 lds_frag(const unsigned short* p) {  // ds_read_b128
  s16x8 v = *reinterpret_cast<const s16x8*>(p);
  return __builtin_bit_cast(bf16x8, v);
}
__device__ __forceinline__ void st_coh16(unsigned short* p, unsigned short v) {
  __hip_atomic_store(p, v, __ATOMIC_RELAXED, __HIP_MEMORY_SCOPE_AGENT);
}
__device__ __forceinline__ f32x4 mfma16(bf16x8 a, bf16x8 b, f32x4 c) {
  return __builtin_amdgcn_mfma_f32_16x16x32_bf16(a, b, c, 0, 0, 0);
}
__device__ __forceinline__ unsigned short tobf(float f) {
  return __builtin_bit_cast(unsigned short, (__bf16)f);
}
__device__ __forceinline__ float fast_tanh(float v) {
  float e = __expf(2.0f * v);
  return 1.0f - 2.0f / (e + 1.0f);
}

// ---------------- prologue kernels ----------------
__global__ void init_flags_k(unsigned* f) {
  int i = blockIdx.x * 256 + threadIdx.x;
  if (i < NGROUP * GSIZE * FSTRIDE) f[i] = 0u;
}

// Pack W[K][N] fp32 -> bf16 in MFMA B-fragment order (validated rounds 1-3):
// packed[((nt*(K/32)+kb)*64 + lane)*8 + j] = W[kb*32 + (lane>>4)*8 + j][nt*16 + (lane&15)]
__global__ void swizzle_w_k(const float* __restrict__ W, unsigned short* __restrict__ Wp,
                            int N, int kblog) {
  int idx = blockIdx.x * 256 + threadIdx.x;
  int j = idx & 7;
  int l = (idx >> 3) & 63;
  int rem = idx >> 9;
  int kb = rem & ((1 << kblog) - 1);
  int nt = rem >> kblog;
  int k = kb * 32 + ((l >> 4) << 3) + j;
  int n = (nt << 4) + (l & 15);
  Wp[idx] = tobf(W[(size_t)k * N + n]);
}

// ---------------- split-phase group barrier (32 WGs), MALL-coherent padded flags ----
__device__ __forceinline__ void bar_arrive(unsigned* gf, int gn, unsigned gen) {
  asm volatile("s_waitcnt vmcnt(0)" ::: "memory");   // this wave's coherent stores drained
  __syncthreads();                                   // all waves drained
  if (threadIdx.x == 0)
    __hip_atomic_store(&gf[gn * FSTRIDE], gen, __ATOMIC_RELAXED, __HIP_MEMORY_SCOPE_AGENT);
}
__device__ __forceinline__ void bar_wait(unsigned* gf, unsigned gen) {
  if (threadIdx.x < GSIZE) {
    while (__hip_atomic_load(&gf[threadIdx.x * FSTRIDE], __ATOMIC_RELAXED,
                             __HIP_MEMORY_SCOPE_AGENT) < gen)
      __builtin_amdgcn_s_sleep(1);
  }
  __syncthreads();
}

// ---------------- staging: batched coherent loads + deferred LDS commit ----------------
// 16 rows x 128 ull chunk; 256 threads x 8 ull. v[] carries loads across compute (dbuf).
__device__ __forceinline__ void issue_l1(const ull* __restrict__ g, int tid, ull v[8]) {
  #pragma unroll
  for (int j = 0; j < 8; ++j)     // u is contiguous: 16 rows x 128 ull
    v[j] = __hip_atomic_load(g + j * NTHR + tid, __ATOMIC_RELAXED, __HIP_MEMORY_SCOPE_AGENT);
}
__device__ __forceinline__ void issue_chunk(const ull* __restrict__ g, int tid, ull v[8]) {
  #pragma unroll
  for (int j = 0; j < 8; ++j) {   // h rows stride 512 ull; chunk = 128 ull of each row
    int i = j * NTHR + tid;
    v[j] = __hip_atomic_load(g + (size_t)(i >> 7) * 512 + (i & 127),
                             __ATOMIC_RELAXED, __HIP_MEMORY_SCOPE_AGENT);
  }
}
__device__ __forceinline__ void commit(ull* __restrict__ lds, int tid, const ull v[8]) {
  #pragma unroll
  for (int j = 0; j < 8; ++j) {
    int i = j * NTHR + tid;
    lds[(i >> 7) * RSU + (i & 127)] = v[j];
  }
}

// ---------------- persistent ODE kernel ----------------
// 8 groups x 32 WGs. Group g owns batch rows [16g,16g+16). gn%8 -> XCD weight affinity.
__global__ __launch_bounds__(NTHR, 1) void ode_persist_k(
    const float* __restrict__ x, const float* __restrict__ b1,
    const float* __restrict__ b2, const float* __restrict__ b3,
    float* __restrict__ out, unsigned char* __restrict__ ws) {
  const int wg = blockIdx.x, tid = threadIdx.x;
  const int g = wg >> 5, gn = wg & 31;
  const int wave = tid >> 6, lane = tid & 63;
  const int lhi = lane >> 4, llo = lane & 15;

  unsigned* gflags = (unsigned*)(ws + OFF_FLAGS) + g * GSIZE * FSTRIDE;
  const unsigned short* W1p = (const unsigned short*)(ws + OFF_W1P);
  const unsigned short* W2p = (const unsigned short*)(ws + OFF_W2P);
  const unsigned short* W3p = (const unsigned short*)(ws + OFF_W3P);
  const ull* ubuf_u = (const ull*)(ws + OFF_U)  + (size_t)g * (M_ * C_ / 4);
  const ull* h1_u   = (const ull*)(ws + OFF_H1) + (size_t)g * (M_ * H_ / 4);
  const ull* h2_u   = (const ull*)(ws + OFF_H2) + (size_t)g * (M_ * H_ / 4);
  unsigned short* ubuf_s = (unsigned short*)(ws + OFF_U)  + (size_t)g * M_ * C_;
  unsigned short* h1_s   = (unsigned short*)(ws + OFF_H1) + (size_t)g * M_ * H_;
  unsigned short* h2_s   = (unsigned short*)(ws + OFF_H2) + (size_t)g * M_ * H_;

  __shared__ alignas(16) ull atile[2][M_ * RSU];   // 2 x 16.75 KB
  __shared__ float red[4][256];
  __shared__ float ytile[256], k1t[256], k2t[256], k3t[256];

  // weight bases (B-fragment layout)
  const int n16 = gn * 4 + wave;                    // layers 1,2 column tile
  const unsigned short* bp1 = W1p + (size_t)n16 * 16 * 512 + lane * 8;
  const unsigned short* bp2 = W2p + (size_t)n16 * 64 * 512 + lane * 8;
  const unsigned short* bp3 = W3p + (size_t)gn  * 64 * 512 + lane * 8;

  // ---- register-resident W1 and W3 slices (loaded once, zero L2 traffic after) ----
  bf16x8 w1r[16], w3r[16];
  #pragma unroll
  for (int kb = 0; kb < 16; ++kb) w1r[kb] = ld_frag(bp1 + kb * 512);
  #pragma unroll
  for (int q = 0; q < 16; ++q)    // q = c*4+jj -> frag (c*16 + wave*4 + jj)
    w3r[q] = ld_frag(bp3 + ((q >> 2) * 16 + wave * 4 + (q & 3)) * 512);

  // ---- init: y tile from x, out[:,0,:], ubuf = bf16(y) ----
  {
    int row = tid >> 4, c16 = tid & 15;
    int col = gn * 16 + c16;
    int b = g * M_ + row;
    float v = x[(size_t)b * (T_ * C_) + col];
    ytile[tid] = v;
    out[(size_t)b * (T_ * C_) + col] = v;
    st_coh16(&ubuf_s[row * C_ + col], tobf(v));
  }
  unsigned gen = 0;
  bar_arrive(gflags, gn, ++gen);
  bar_wait(gflags, gen);

  ull v[8];
  #pragma unroll 1
  for (int t = 0; t < T_ - 1; ++t) {
    #pragma unroll 1
    for (int sub = 0; sub < 3; ++sub) {
      #pragma unroll 1
      for (int st = 0; st < 4; ++st) {
        // ================= layer 1: [16x512]@[512x2048], tanh =================
        issue_l1(ubuf_u, tid, v);
        commit(atile[0], tid, v);
        __syncthreads();
        {
          f32x4 acc = {0.f, 0.f, 0.f, 0.f};
          const unsigned short* al = (const unsigned short*)atile[0] + llo * RSS + lhi * 8;
          #pragma unroll
          for (int kb = 0; kb < 16; ++kb)
            acc = mfma16(lds_frag(al + kb * 32), w1r[kb], acc);
          const int col = n16 * 16 + llo;
          const float bb = b1[col];
          #pragma unroll
          for (int r = 0; r < 4; ++r)
            st_coh16(&h1_s[(lhi * 4 + r) * H_ + col], tobf(fast_tanh(acc[r] + bb)));
        }
        bar_arrive(gflags, gn, ++gen);
        // prefetch first 8 W2 fragments across the barrier wait (L2-resident)
        bf16x8 pf[8];
        #pragma unroll
        for (int q = 0; q < 8; ++q) pf[q] = ld_frag(bp2 + q * 512);
        bar_wait(gflags, gen);

        // ================= layer 2: [16x2048]@[2048x2048], tanh =================
        {
          f32x4 acc = {0.f, 0.f, 0.f, 0.f};
          issue_chunk(h1_u, tid, v);
          commit(atile[0], tid, v);
          __syncthreads();
          // chunk 0 (kb<8 from prefetch), prefetch chunk 1 staging
          issue_chunk(h1_u + 128, tid, v);
          {
            const unsigned short* al = (const unsigned short*)atile[0] + llo * RSS + lhi * 8;
            #pragma unroll
            for (int kb = 0; kb < 8; ++kb)
              acc = mfma16(lds_frag(al + kb * 32), pf[kb], acc);
            #pragma unroll
            for (int kb = 8; kb < 16; ++kb)
              acc = mfma16(lds_frag(al + kb * 32), ld_frag(bp2 + kb * 512), acc);
          }
          commit(atile[1], tid, v);
          __syncthreads();
          #pragma unroll
          for (int c = 1; c < 4; ++c) {
            if (c < 3) issue_chunk(h1_u + (c + 1) * 128, tid, v);
            const unsigned short* al = (const unsigned short*)atile[c & 1] + llo * RSS + lhi * 8;
            #pragma unroll
            for (int kb = 0; kb < 16; ++kb)
              acc = mfma16(lds_frag(al + kb * 32), ld_frag(bp2 + (c * 16 + kb) * 512), acc);
            if (c < 3) commit(atile[(c + 1) & 1], tid, v);
            __syncthreads();
          }
          const int col = n16 * 16 + llo;
          const float bb = b2[col];
          #pragma unroll
          for (int r = 0; r < 4; ++r)
            st_coh16(&h2_s[(lhi * 4 + r) * H_ + col], tobf(fast_tanh(acc[r] + bb)));
        }
        bar_arrive(gflags, gn, ++gen);
        bar_wait(gflags, gen);

        // ======= layer 3: [16x2048]@[2048x512], wave K-split, RK4 epilogue =======
        {
          f32x4 acc = {0.f, 0.f, 0.f, 0.f};
          issue_chunk(h2_u, tid, v);
          commit(atile[0], tid, v);
          __syncthreads();
          #pragma unroll
          for (int c = 0; c < 4; ++c) {
            if (c < 3) issue_chunk(h2_u + (c + 1) * 128, tid, v);
            const unsigned short* al = (const unsigned short*)atile[c & 1] + llo * RSS + lhi * 8;
            #pragma unroll
            for (int jj = 0; jj < 4; ++jj)
              acc = mfma16(lds_frag(al + (wave * 4 + jj) * 32), w3r[c * 4 + jj], acc);
            if (c < 3) commit(atile[(c + 1) & 1], tid, v);
            __syncthreads();
          }
          #pragma unroll
          for (int r = 0; r < 4; ++r) red[wave][(lhi * 4 + r) * 16 + llo] = acc[r];
          __syncthreads();
          if (wave == 0) {
            const float dt = DT_F;
            const float bb = b3[gn * 16 + llo];
            #pragma unroll
            for (int r = 0; r < 4; ++r) {
              int row = lhi * 4 + r;
              int i = row * 16 + llo;
              float z = red[0][i] + red[1][i] + red[2][i] + red[3][i] + bb;
              float yv = ytile[i];
              unsigned short* up = &ubuf_s[row * C_ + gn * 16 + llo];
              if (st == 0)      { k1t[i] = z; st_coh16(up, tobf(yv + 0.5f * dt * z)); }
              else if (st == 1) { k2t[i] = z; st_coh16(up, tobf(yv + 0.5f * dt * z)); }
              else if (st == 2) { k3t[i] = z; st_coh16(up, tobf(yv + dt * z)); }
              else {
                float yn = yv + (dt * (1.0f / 6.0f)) * (k1t[i] + 2.f * k2t[i] + 2.f * k3t[i] + z);
                ytile[i] = yn;
                st_coh16(up, tobf(yn));
                if (sub == 2)
                  out[(size_t)(g * M_ + row) * (T_ * C_) + (size_t)(t + 1) * C_ + gn * 16 + llo] = yn;
              }
            }
          }
        }
        bar_arrive(gflags, gn, ++gen);
        bar_wait(gflags, gen);
      }
    }
  }
}

// ---------------- host ----------------
extern "C" void kernel_launch(void* const* d_in, const int* in_sizes, int n_in,
                              void* d_out, int out_size, void* d_ws, size_t ws_size,
                              hipStream_t stream) {
  (void)in_sizes; (void)n_in; (void)out_size; (void)ws_size;
  const float* x  = (const float*)d_in[0];
  const float* W1 = (const float*)d_in[1];
  const float* b1 = (const float*)d_in[2];
  const float* W2 = (const float*)d_in[3];
  const float* b2 = (const float*)d_in[4];
  const float* W3 = (const float*)d_in[5];
  const float* b3 = (const float*)d_in[6];
  float* out = (float*)d_out;
  unsigned char* ws = (unsigned char*)d_ws;

  init_flags_k<<<16, 256, 0, stream>>>((unsigned*)(ws + OFF_FLAGS));
  // W1: K=512 (kblog=4), N=2048 ; W2: K=2048 (kblog=6), N=2048 ; W3: K=2048 (kblog=6), N=512
  swizzle_w_k<<<(C_ * H_) / 256, 256, 0, stream>>>(W1, (unsigned short*)(ws + OFF_W1P), H_, 4);
  swizzle_w_k<<<(H_ * H_) / 256, 256, 0, stream>>>(W2, (unsigned short*)(ws + OFF_W2P), H_, 6);
  swizzle_w_k<<<(H_ * C_) / 256, 256, 0, stream>>>(W3, (unsigned short*)(ws + OFF_W3P), C_, 6);

  ode_persist_k<<<NWG, NTHR, 0, stream>>>(x, b1, b2, b3, out, ws);
}

// Round 5
// 43781.555 us; speedup vs baseline: 5.1648x; 1.1842x over previous
//
#include <hip/hip_runtime.h>
#include <hip/hip_bf16.h>
#include <cstdint>

#define B_ 128
#define T_ 256
#define C_ 512
#define H_ 2048
#define NWG 256
#define NTHR 256
#define NGROUP 8
#define GSIZE 32        // WGs per row-group
#define M_ 16           // batch rows per group
#define FSTRIDE 16      // flag padding (dwords) -> 64 B per flag
#define RSU1 132        // atile row stride in ull: 264 dw == 8 mod 32 -> uniform banks for b128
#define RSS1 528        // row stride in shorts
// DT = (1/(T-1))/N_SUB = 1/765
#define DT_F 0.0013071895424836601f

typedef __bf16 bf16x8 __attribute__((ext_vector_type(8)));
typedef short s16x8 __attribute__((ext_vector_type(8)));
typedef float f32x4 __attribute__((ext_vector_type(4)));
typedef unsigned long long ull;

// ---------------- workspace layout (bytes) ----------------
enum : size_t {
  OFF_FLAGS = 0,                                    // 8 groups * 32 flags * 64 B
  OFF_W1P = 32768,
  OFF_W2P = OFF_W1P + (size_t)C_ * H_ * 2,          // 2 MB
  OFF_W3P = OFF_W2P + (size_t)H_ * H_ * 2,          // 8 MB
  OFF_U   = OFF_W3P + (size_t)H_ * C_ * 2,          // 2 MB
  OFF_H1  = OFF_U   + (size_t)NGROUP * M_ * C_ * 2, // 128 KB
  OFF_H2  = OFF_H1  + (size_t)NGROUP * M_ * H_ * 2, // 512 KB
  WS_END  = OFF_H2  + (size_t)NGROUP * M_ * H_ * 2  // ~13.4 MB
};

__device__ __forceinline__ bf16x8 ld_frag(const unsigned short* p) {   // cached (weights)
  s16x8 v = *reinterpret_cast<const s16x8*>(p);
  return __builtin_bit_cast(bf16x8, v);
}
__device__ __forceinline__ bf16x8 lds_frag(const unsigned short* p) {  // ds_read_b128
  s16x8 v = *reinterpret_cast<const s16x8*>(p);
  return __builtin_bit_cast(bf16x8, v);
}
__device__ __forceinline__ void st_coh16(unsigned short* p, unsigned short v) {
  __hip_atomic_store(p, v, __ATOMIC_RELAXED, __HIP_MEMORY_SCOPE_AGENT);
}
__device__ __forceinline__ f32x4 mfma16(bf16x8 a, bf16x8 b, f32x4 c) {
  return __builtin_amdgcn_mfma_f32_16x16x32_bf16(a, b, c, 0, 0, 0);
}
__device__ __forceinline__ unsigned short tobf(float f) {
  return __builtin_bit_cast(unsigned short, (__bf16)f);
}
__device__ __forceinline__ float fast_tanh(float v) {
  float e = __expf(2.0f * v);
  return 1.0f - 2.0f / (e + 1.0f);
}

// ---------------- prologue kernels ----------------
__global__ void init_flags_k(unsigned* f) {
  int i = blockIdx.x * 256 + threadIdx.x;
  if (i < NGROUP * GSIZE * FSTRIDE) f[i] = 0u;
}

// Pack W[K][N] fp32 -> bf16 in MFMA B-fragment order (validated rounds 1-4):
// packed[((nt*(K/32)+kb)*64 + lane)*8 + j] = W[kb*32 + (lane>>4)*8 + j][nt*16 + (lane&15)]
__global__ void swizzle_w_k(const float* __restrict__ W, unsigned short* __restrict__ Wp,
                            int N, int kblog) {
  int idx = blockIdx.x * 256 + threadIdx.x;
  int j = idx & 7;
  int l = (idx >> 3) & 63;
  int rem = idx >> 9;
  int kb = rem & ((1 << kblog) - 1);
  int nt = rem >> kblog;
  int k = kb * 32 + ((l >> 4) << 3) + j;
  int n = (nt << 4) + (l & 15);
  Wp[idx] = tobf(W[(size_t)k * N + n]);
}

// ---------------- split-phase group barrier (32 WGs), MALL-coherent padded flags ----
__device__ __forceinline__ void bar_arrive(unsigned* gf, int gn, unsigned gen) {
  asm volatile("s_waitcnt vmcnt(0)" ::: "memory");   // coherent stores drained
  __syncthreads();                                   // all waves drained
  if (threadIdx.x == 0)
    __hip_atomic_store(&gf[gn * FSTRIDE], gen, __ATOMIC_RELAXED, __HIP_MEMORY_SCOPE_AGENT);
}
__device__ __forceinline__ void bar_wait(unsigned* gf, unsigned gen) {
  if (threadIdx.x < GSIZE) {
    while (__hip_atomic_load(&gf[threadIdx.x * FSTRIDE], __ATOMIC_RELAXED,
                             __HIP_MEMORY_SCOPE_AGENT) < gen)
      __builtin_amdgcn_s_sleep(1);
  }
  __syncthreads();
}

// ---------------- staging: batched coherent loads + deferred LDS commit ----------------
// chunk = 16 rows x 128 ull; 256 threads x 8 ull each.
__device__ __forceinline__ void issue_u(const ull* __restrict__ g, int tid, ull v[8]) {
  #pragma unroll
  for (int j = 0; j < 8; ++j)     // u is contiguous: 16 rows x 128 ull
    v[j] = __hip_atomic_load(g + j * NTHR + tid, __ATOMIC_RELAXED, __HIP_MEMORY_SCOPE_AGENT);
}
__device__ __forceinline__ void issue_c(const ull* __restrict__ g, int tid, ull v[8]) {
  #pragma unroll
  for (int j = 0; j < 8; ++j) {   // h rows stride 512 ull; chunk = 128 ull of each row
    int i = j * NTHR + tid;
    v[j] = __hip_atomic_load(g + (size_t)(i >> 7) * 512 + (i & 127),
                             __ATOMIC_RELAXED, __HIP_MEMORY_SCOPE_AGENT);
  }
}
__device__ __forceinline__ void commit(ull* __restrict__ lds, int tid, const ull v[8]) {
  #pragma unroll
  for (int j = 0; j < 8; ++j) {
    int i = j * NTHR + tid;
    lds[(i >> 7) * RSU1 + (i & 127)] = v[j];
  }
}

// compile-time-indexed compute macros (keep w2r/w3r register-resident!)
#define L2CHUNK(c, buf) {                                                     \
  const unsigned short* al = (const unsigned short*)atile[buf] + llo * RSS1 + lhi * 8; \
  _Pragma("unroll")                                                           \
  for (int jj = 0; jj < 8; ++jj) {                                            \
    acc0 = mfma16(lds_frag(al + (2 * jj) * 32),     w2r[(c) * 16 + 2 * jj],     acc0); \
    acc1 = mfma16(lds_frag(al + (2 * jj + 1) * 32), w2r[(c) * 16 + 2 * jj + 1], acc1); \
  } }

#define L3CHUNK(c, buf) {                                                     \
  const unsigned short* al = (const unsigned short*)atile[buf] + llo * RSS1 + lhi * 8; \
  _Pragma("unroll")                                                           \
  for (int jj = 0; jj < 2; ++jj) {                                            \
    acc0 = mfma16(lds_frag(al + (wave * 4 + 2 * jj) * 32),     w3r[(c) * 4 + 2 * jj],     acc0); \
    acc1 = mfma16(lds_frag(al + (wave * 4 + 2 * jj + 1) * 32), w3r[(c) * 4 + 2 * jj + 1], acc1); \
  } }

// ---------------- persistent ODE kernel ----------------
// 8 groups x 32 WGs. Group g owns batch rows [16g,16g+16). gn%8 -> XCD weight affinity.
__global__ __launch_bounds__(NTHR, 1) void ode_persist_k(
    const float* __restrict__ x, const float* __restrict__ b1,
    const float* __restrict__ b2, const float* __restrict__ b3,
    float* __restrict__ out, unsigned char* __restrict__ ws) {
  const int wg = blockIdx.x, tid = threadIdx.x;
  const int g = wg >> 5, gn = wg & 31;
  const int wave = tid >> 6, lane = tid & 63;
  const int lhi = lane >> 4, llo = lane & 15;

  unsigned* gflags = (unsigned*)(ws + OFF_FLAGS) + g * GSIZE * FSTRIDE;
  const unsigned short* W1p = (const unsigned short*)(ws + OFF_W1P);
  const unsigned short* W2p = (const unsigned short*)(ws + OFF_W2P);
  const unsigned short* W3p = (const unsigned short*)(ws + OFF_W3P);
  const ull* ubuf_u = (const ull*)(ws + OFF_U)  + (size_t)g * (M_ * C_ / 4);
  const ull* h1_u   = (const ull*)(ws + OFF_H1) + (size_t)g * (M_ * H_ / 4);
  const ull* h2_u   = (const ull*)(ws + OFF_H2) + (size_t)g * (M_ * H_ / 4);
  unsigned short* ubuf_s = (unsigned short*)(ws + OFF_U)  + (size_t)g * M_ * C_;
  unsigned short* h1_s   = (unsigned short*)(ws + OFF_H1) + (size_t)g * M_ * H_;
  unsigned short* h2_s   = (unsigned short*)(ws + OFF_H2) + (size_t)g * M_ * H_;

  __shared__ alignas(16) ull atile[2][M_ * RSU1];   // 2 x 16.5 KB
  __shared__ float red[4][256];
  __shared__ float ytile[256], k1t[256], k2t[256], k3t[256];

  // weight bases (B-fragment layout)
  const int n16 = gn * 4 + wave;                    // layers 1,2 column tile
  const unsigned short* bp1 = W1p + (size_t)n16 * 16 * 512 + lane * 8;
  const unsigned short* bp2 = W2p + (size_t)n16 * 64 * 512 + lane * 8;
  const unsigned short* bp3 = W3p + (size_t)gn  * 64 * 512 + lane * 8;

  // ---- register-resident W2 (256 VGPR) and W3 (64 VGPR) slices ----
  bf16x8 w2r[64], w3r[16];
  #pragma unroll
  for (int kb = 0; kb < 64; ++kb) w2r[kb] = ld_frag(bp2 + kb * 512);
  #pragma unroll
  for (int q = 0; q < 16; ++q)    // q = c*4+jj -> global kb = c*16 + wave*4 + jj
    w3r[q] = ld_frag(bp3 + ((q >> 2) * 16 + wave * 4 + (q & 3)) * 512);

  // biases: fixed per lane -> hoist to registers
  const float bb1 = b1[n16 * 16 + llo];
  const float bb2 = b2[n16 * 16 + llo];
  const float bb3 = b3[gn * 16 + llo];

  // ---- init: y tile from x, out[:,0,:], ubuf = bf16(y) ----
  {
    int row = tid >> 4, c16 = tid & 15;
    int col = gn * 16 + c16;
    int b = g * M_ + row;
    float v = x[(size_t)b * (T_ * C_) + col];
    ytile[tid] = v;
    out[(size_t)b * (T_ * C_) + col] = v;
    st_coh16(&ubuf_s[row * C_ + col], tobf(v));
  }
  unsigned gen = 0;
  bar_arrive(gflags, gn, ++gen);
  bar_wait(gflags, gen);

  ull va[8], vb[8];
  #pragma unroll 1
  for (int t = 0; t < T_ - 1; ++t) {
    #pragma unroll 1
    for (int sub = 0; sub < 3; ++sub) {
      #pragma unroll 1
      for (int st = 0; st < 4; ++st) {
        // ================= layer 1: [16x512]@[512x2048], tanh =================
        {
          issue_u(ubuf_u, tid, va);
          bf16x8 w1f[16];                       // W1 streamed: L2-hit, hidden by u's MALL RT
          #pragma unroll
          for (int kb = 0; kb < 16; ++kb) w1f[kb] = ld_frag(bp1 + kb * 512);
          commit(atile[0], tid, va);
          __syncthreads();
          f32x4 acc0 = {0.f, 0.f, 0.f, 0.f}, acc1 = {0.f, 0.f, 0.f, 0.f};
          const unsigned short* al = (const unsigned short*)atile[0] + llo * RSS1 + lhi * 8;
          #pragma unroll
          for (int jj = 0; jj < 8; ++jj) {
            acc0 = mfma16(lds_frag(al + (2 * jj) * 32),     w1f[2 * jj],     acc0);
            acc1 = mfma16(lds_frag(al + (2 * jj + 1) * 32), w1f[2 * jj + 1], acc1);
          }
          f32x4 a = acc0 + acc1;
          const int col = n16 * 16 + llo;
          #pragma unroll
          for (int r = 0; r < 4; ++r)
            st_coh16(&h1_s[(lhi * 4 + r) * H_ + col], tobf(fast_tanh(a[r] + bb1)));
        }
        bar_arrive(gflags, gn, ++gen);
        bar_wait(gflags, gen);

        // ========== layer 2: [16x2048]@[2048x2048], tanh, weights in VGPRs ==========
        {
          f32x4 acc0 = {0.f, 0.f, 0.f, 0.f}, acc1 = {0.f, 0.f, 0.f, 0.f};
          issue_c(h1_u,       tid, va);
          issue_c(h1_u + 128, tid, vb);          // 2-deep staging pipeline
          commit(atile[0], tid, va);
          __syncthreads();
          issue_c(h1_u + 256, tid, va);
          L2CHUNK(0, 0);
          commit(atile[1], tid, vb);
          __syncthreads();
          issue_c(h1_u + 384, tid, vb);
          L2CHUNK(1, 1);
          commit(atile[0], tid, va);
          __syncthreads();
          L2CHUNK(2, 0);
          commit(atile[1], tid, vb);
          __syncthreads();
          L2CHUNK(3, 1);
          f32x4 a = acc0 + acc1;
          const int col = n16 * 16 + llo;
          #pragma unroll
          for (int r = 0; r < 4; ++r)
            st_coh16(&h2_s[(lhi * 4 + r) * H_ + col], tobf(fast_tanh(a[r] + bb2)));
        }
        bar_arrive(gflags, gn, ++gen);
        bar_wait(gflags, gen);

        // ==== layer 3: [16x2048]@[2048x512], wave K-split, weights in VGPRs, RK4 ====
        {
          f32x4 acc0 = {0.f, 0.f, 0.f, 0.f}, acc1 = {0.f, 0.f, 0.f, 0.f};
          issue_c(h2_u,       tid, va);
          issue_c(h2_u + 128, tid, vb);
          commit(atile[0], tid, va);
          __syncthreads();
          issue_c(h2_u + 256, tid, va);
          L3CHUNK(0, 0);
          commit(atile[1], tid, vb);
          __syncthreads();
          issue_c(h2_u + 384, tid, vb);
          L3CHUNK(1, 1);
          commit(atile[0], tid, va);
          __syncthreads();
          L3CHUNK(2, 0);
          commit(atile[1], tid, vb);
          __syncthreads();
          L3CHUNK(3, 1);
          f32x4 a = acc0 + acc1;
          #pragma unroll
          for (int r = 0; r < 4; ++r) red[wave][(lhi * 4 + r) * 16 + llo] = a[r];
          __syncthreads();
          if (wave == 0) {
            const float dt = DT_F;
            #pragma unroll
            for (int r = 0; r < 4; ++r) {
              int row = lhi * 4 + r;
              int i = row * 16 + llo;
              float z = red[0][i] + red[1][i] + red[2][i] + red[3][i] + bb3;
              float yv = ytile[i];
              unsigned short* up = &ubuf_s[row * C_ + gn * 16 + llo];
              if (st == 0)      { k1t[i] = z; st_coh16(up, tobf(yv + 0.5f * dt * z)); }
              else if (st == 1) { k2t[i] = z; st_coh16(up, tobf(yv + 0.5f * dt * z)); }
              else if (st == 2) { k3t[i] = z; st_coh16(up, tobf(yv + dt * z)); }
              else {
                float yn = yv + (dt * (1.0f / 6.0f)) * (k1t[i] + 2.f * k2t[i] + 2.f * k3t[i] + z);
                ytile[i] = yn;
                st_coh16(up, tobf(yn));
                if (sub == 2)
                  out[(size_t)(g * M_ + row) * (T_ * C_) + (size_t)(t + 1) * C_ + gn * 16 + llo] = yn;
              }
            }
          }
        }
        bar_arrive(gflags, gn, ++gen);
        bar_wait(gflags, gen);
      }
    }
  }
}

// ---------------- host ----------------
extern "C" void kernel_launch(void* const* d_in, const int* in_sizes, int n_in,
                              void* d_out, int out_size, void* d_ws, size_t ws_size,
                              hipStream_t stream) {
  (void)in_sizes; (void)n_in; (void)out_size; (void)ws_size;
  const float* x  = (const float*)d_in[0];
  const float* W1 = (const float*)d_in[1];
  const float* b1 = (const float*)d_in[2];
  const float* W2 = (const float*)d_in[3];
  const float* b2 = (const float*)d_in[4];
  const float* W3 = (const float*)d_in[5];
  const float* b3 = (const float*)d_in[6];
  float* out = (float*)d_out;
  unsigned char* ws = (unsigned char*)d_ws;

  init_flags_k<<<16, 256, 0, stream>>>((unsigned*)(ws + OFF_FLAGS));
  // W1: K=512 (kblog=4), N=2048 ; W2: K=2048 (kblog=6), N=2048 ; W3: K=2048 (kblog=6), N=512
  swizzle_w_k<<<(C_ * H_) / 256, 256, 0, stream>>>(W1, (unsigned short*)(ws + OFF_W1P), H_, 4);
  swizzle_w_k<<<(H_ * H_) / 256, 256, 0, stream>>>(W2, (unsigned short*)(ws + OFF_W2P), H_, 6);
  swizzle_w_k<<<(H_ * C_) / 256, 256, 0, stream>>>(W3, (unsigned short*)(ws + OFF_W3P), C_, 6);

  ode_persist_k<<<NWG, NTHR, 0, stream>>>(x, b1, b2, b3, out, ws);
}